// Round 9
// baseline (303.988 us; speedup 1.0000x reference)
//
#include <hip/hip_runtime.h>
#include <math.h>

namespace {

constexpr int kB  = 2;
constexpr int kS  = 2048;
constexpr int kD  = 512;
constexpr int kH  = 8;
constexpr int kDK = 64;
constexpr int kM  = kB * kS;   // 4096 rows
constexpr int kBH = kB * kH;   // 16

typedef __attribute__((ext_vector_type(8))) short bf16x8;
typedef __attribute__((ext_vector_type(4))) float f32x4;

__device__ __forceinline__ float wave_sum64(float v) {
#pragma unroll
    for (int o = 32; o > 0; o >>= 1) v += __shfl_xor(v, o, 64);
    return v;
}

__device__ __forceinline__ unsigned short f2bf(float f) {
    unsigned u = __float_as_uint(f);
    unsigned r = (u + 0x7FFF + ((u >> 16) & 1)) >> 16;   // round-to-nearest-even
    return (unsigned short)r;
}
__device__ __forceinline__ float bf2f(unsigned short h) {
    return __uint_as_float(((unsigned)h) << 16);
}

#define MAXN_F  ((float)(1.0 - 1e-5))
#define ACLIP_F ((float)(1.0 - 1e-7))

// ---- GEMM via split-bf16 MFMA: Y(4096x512) = X(4096x512) @ W(512x512)^T ----
__global__ __launch_bounds__(256) void gemm_mfma(const float* __restrict__ X,
                                                 const float* __restrict__ W,
                                                 float* __restrict__ Y) {
    __shared__ unsigned short Ah[64 * 64], Al[64 * 64], Bh[64 * 64], Bl[64 * 64];
    const int m0 = blockIdx.x * 64;
    const int n0 = blockIdx.y * 64;
    const int tid = threadIdx.x;
    const int w = tid >> 6, l = tid & 63;
    const int lr = l & 15, lh = l >> 4;
    const int sr = tid >> 2;          // staging row 0..63
    const int sk = (tid & 3) * 16;    // staging k base (16 elems/thread)
    float4 xr[4], wr[4];
#pragma unroll
    for (int i = 0; i < 4; ++i) {
        xr[i] = *(const float4*)(X + (size_t)(m0 + sr) * 512 + sk + i * 4);
        wr[i] = *(const float4*)(W + (size_t)(n0 + sr) * 512 + sk + i * 4);
    }
    f32x4 acc[4];
#pragma unroll
    for (int j = 0; j < 4; ++j) acc[j] = (f32x4){0.f, 0.f, 0.f, 0.f};

    for (int c = 0; c < 8; ++c) {
        if (c) __syncthreads();       // previous MFMA done reading LDS
        {
            unsigned hx[8], lx[8], hw_[8], lw_[8];
#pragma unroll
            for (int t = 0; t < 8; ++t) {
                float e0 = ((const float*)&xr[t >> 1])[(t & 1) * 2 + 0];
                float e1 = ((const float*)&xr[t >> 1])[(t & 1) * 2 + 1];
                unsigned short h0 = f2bf(e0), h1 = f2bf(e1);
                hx[t] = (unsigned)h0 | ((unsigned)h1 << 16);
                lx[t] = (unsigned)f2bf(e0 - bf2f(h0)) | ((unsigned)f2bf(e1 - bf2f(h1)) << 16);
                float f0 = ((const float*)&wr[t >> 1])[(t & 1) * 2 + 0];
                float f1 = ((const float*)&wr[t >> 1])[(t & 1) * 2 + 1];
                unsigned short g0 = f2bf(f0), g1 = f2bf(f1);
                hw_[t] = (unsigned)g0 | ((unsigned)g1 << 16);
                lw_[t] = (unsigned)f2bf(f0 - bf2f(g0)) | ((unsigned)f2bf(f1 - bf2f(g1)) << 16);
            }
            const int ga = (sk >> 3) ^ (sr & 7);
            const int gb = ((sk >> 3) + 1) ^ (sr & 7);
            *(uint4*)&Ah[sr * 64 + ga * 8] = make_uint4(hx[0], hx[1], hx[2], hx[3]);
            *(uint4*)&Ah[sr * 64 + gb * 8] = make_uint4(hx[4], hx[5], hx[6], hx[7]);
            *(uint4*)&Al[sr * 64 + ga * 8] = make_uint4(lx[0], lx[1], lx[2], lx[3]);
            *(uint4*)&Al[sr * 64 + gb * 8] = make_uint4(lx[4], lx[5], lx[6], lx[7]);
            *(uint4*)&Bh[sr * 64 + ga * 8] = make_uint4(hw_[0], hw_[1], hw_[2], hw_[3]);
            *(uint4*)&Bh[sr * 64 + gb * 8] = make_uint4(hw_[4], hw_[5], hw_[6], hw_[7]);
            *(uint4*)&Bl[sr * 64 + ga * 8] = make_uint4(lw_[0], lw_[1], lw_[2], lw_[3]);
            *(uint4*)&Bl[sr * 64 + gb * 8] = make_uint4(lw_[4], lw_[5], lw_[6], lw_[7]);
        }
        if (c < 7) {
            const int k1 = (c + 1) * 64;
#pragma unroll
            for (int i = 0; i < 4; ++i) {
                xr[i] = *(const float4*)(X + (size_t)(m0 + sr) * 512 + k1 + sk + i * 4);
                wr[i] = *(const float4*)(W + (size_t)(n0 + sr) * 512 + k1 + sk + i * 4);
            }
        }
        __syncthreads();
#pragma unroll
        for (int ks = 0; ks < 2; ++ks) {
            const int kb = ks * 4 + lh;
            const int row = w * 16 + lr;
            const int aoff = row * 64 + ((kb ^ (row & 7)) << 3);
            bf16x8 ah = *(const bf16x8*)&Ah[aoff];
            bf16x8 al = *(const bf16x8*)&Al[aoff];
#pragma unroll
            for (int fn = 0; fn < 4; ++fn) {
                const int col = fn * 16 + lr;
                const int boff = col * 64 + ((kb ^ (col & 7)) << 3);
                bf16x8 bh8 = *(const bf16x8*)&Bh[boff];
                bf16x8 bl8 = *(const bf16x8*)&Bl[boff];
                acc[fn] = __builtin_amdgcn_mfma_f32_16x16x32_bf16(ah, bh8, acc[fn], 0, 0, 0);
                acc[fn] = __builtin_amdgcn_mfma_f32_16x16x32_bf16(al, bh8, acc[fn], 0, 0, 0);
                acc[fn] = __builtin_amdgcn_mfma_f32_16x16x32_bf16(ah, bl8, acc[fn], 0, 0, 0);
            }
        }
    }
#pragma unroll
    for (int fn = 0; fn < 4; ++fn)
#pragma unroll
        for (int r = 0; r < 4; ++r)
            Y[(size_t)(m0 + w * 16 + lh * 4 + r) * 512 + n0 + fn * 16 + lr] = acc[fn][r];
}

// --------- mobius_linear tail: res=matvec scale; mobius_add(res,b); project ---------
__global__ __launch_bounds__(256) void rowops(const float* __restrict__ X,
                                              const float* __restrict__ MX,
                                              const float* __restrict__ bvec,
                                              float* __restrict__ out) {
    __shared__ float4 red4[4];
    __shared__ float red1[4];
    const int row = blockIdx.x;
    const int tid = threadIdx.x;
    const float2 xv = ((const float2*)(X + (size_t)row * kD))[tid];
    const float2 mv = ((const float2*)(MX + (size_t)row * kD))[tid];
    const float2 bv = ((const float2*)bvec)[tid];
    float sx  = fmaf(xv.x, xv.x, xv.y * xv.y);
    float sm  = fmaf(mv.x, mv.x, mv.y * mv.y);
    float smb = fmaf(mv.x, bv.x, mv.y * bv.y);
    float sb  = fmaf(bv.x, bv.x, bv.y * bv.y);
#pragma unroll
    for (int o = 32; o > 0; o >>= 1) {
        sx  += __shfl_xor(sx, o, 64);
        sm  += __shfl_xor(sm, o, 64);
        smb += __shfl_xor(smb, o, 64);
        sb  += __shfl_xor(sb, o, 64);
    }
    if ((tid & 63) == 0) red4[tid >> 6] = make_float4(sx, sm, smb, sb);
    __syncthreads();
    {
        float4 r0 = red4[0], r1 = red4[1], r2 = red4[2], r3 = red4[3];
        sx  = r0.x + r1.x + r2.x + r3.x;
        sm  = r0.y + r1.y + r2.y + r3.y;
        smb = r0.z + r1.z + r2.z + r3.z;
        sb  = r0.w + r1.w + r2.w + r3.w;
    }
    float xn  = sqrtf(fmaxf(sx, 1e-15f));
    float mxn = sqrtf(fmaxf(sm, 1e-15f));
    float xc  = fminf(xn, ACLIP_F);
    float at  = 0.5f * logf((1.f + xc) / (1.f - xc));       // artanh(xn)
    float sc  = tanhf(mxn / xn * at) / mxn;                 // res = sc * mx
    if (sm == 0.f) sc = 0.f;                                // all(mx==0) branch
    float x2 = sc * sc * sm;
    float xy = sc * smb;
    float y2 = sb;
    float c1 = 1.f + 2.f * xy + y2;
    float c2 = 1.f - x2;
    float den = fmaxf(1.f + 2.f * xy + x2 * y2, 1e-15f);
    float idn = 1.f / den;
    float ux = (c1 * sc * mv.x + c2 * bv.x) * idn;
    float uy = (c1 * sc * mv.y + c2 * bv.y) * idn;
    float su = wave_sum64(fmaf(ux, ux, uy * uy));
    if ((tid & 63) == 0) red1[tid >> 6] = su;
    __syncthreads();
    su = (red1[0] + red1[1]) + (red1[2] + red1[3]);
    float n = sqrtf(fmaxf(su, 1e-15f));
    float f = (n > MAXN_F) ? (MAXN_F / n) : 1.f;
    ((float2*)(out + (size_t)row * kD))[tid] = make_float2(ux * f, uy * f);
}

// ---- prep2: per-head-row |q|^2,|k|^2 + LVbT[bh][n][k] = bf16(logmap0(V_head))^T ----
__global__ __launch_bounds__(256) void prep2(const float* __restrict__ Qp,
                                             const float* __restrict__ Kp,
                                             const float* __restrict__ Vp,
                                             float* __restrict__ qn2,
                                             float* __restrict__ kn2,
                                             unsigned short* __restrict__ LVbT) {
    __shared__ unsigned short T[64][66];   // [n][s_local], 66 -> 2-way banks (free)
    const int bh = blockIdx.x >> 5;
    const int k0 = (blockIdx.x & 31) * 64;
    const int b = bh >> 3, h = bh & 7;
    const int w = threadIdx.x >> 6, l = threadIdx.x & 63;
#pragma unroll 4
    for (int i = 0; i < 16; ++i) {
        const int s = k0 + w * 16 + i;
        const size_t src = (size_t)(b * kS + s) * kD + h * kDK + l;
        float qv = Qp[src], kv = Kp[src], vv = Vp[src];
        float sq = wave_sum64(qv * qv);
        float sk = wave_sum64(kv * kv);
        float sv = wave_sum64(vv * vv);
        if (l == 0) { qn2[(bh << 11) + s] = sq; kn2[(bh << 11) + s] = sk; }
        float yn = sqrtf(fmaxf(sv, 1e-15f));
        float yc = fminf(yn, ACLIP_F);
        float coef = 0.5f * logf((1.f + yc) / (1.f - yc)) / yn;
        T[l][w * 16 + i] = f2bf(vv * coef);
    }
    __syncthreads();
    const int n = threadIdx.x >> 2, kk = (threadIdx.x & 3) * 16;
    const unsigned int* Tr = (const unsigned int*)&T[n][kk];
    unsigned int u0 = Tr[0], u1 = Tr[1], u2 = Tr[2], u3 = Tr[3];
    unsigned int u4 = Tr[4], u5 = Tr[5], u6 = Tr[6], u7 = Tr[7];
    unsigned short* dst = LVbT + (((size_t)(bh * 64 + n)) << 11) + k0 + kk;
    *(uint4*)dst = make_uint4(u0, u1, u2, u3);
    *(uint4*)(dst + 8) = make_uint4(u4, u5, u6, u7);
}

// ---- split_qk: Q,K head-gathered -> hi/lo bf16 planes [bh][s][64] (split-precision) ----
__global__ __launch_bounds__(256) void split_qk(const float* __restrict__ Qp,
                                                const float* __restrict__ Kp,
                                                unsigned short* __restrict__ Qhi,
                                                unsigned short* __restrict__ Qlo,
                                                unsigned short* __restrict__ Khi,
                                                unsigned short* __restrict__ Klo) {
    const int gid  = blockIdx.x * 4 + (threadIdx.x >> 6);
    const int lane = threadIdx.x & 63;
    const int bh = gid >> 11, s = gid & 2047;
    const int b = bh >> 3, h = bh & 7;
    const size_t src = (size_t)(b * kS + s) * kD + h * kDK + lane;
    const size_t dst = ((size_t)gid << 6) + lane;
    float qv = Qp[src];
    unsigned short qh = f2bf(qv);
    Qhi[dst] = qh;
    Qlo[dst] = f2bf(qv - bf2f(qh));
    float kv = Kp[src];
    unsigned short kh = f2bf(kv);
    Khi[dst] = kh;
    Klo[dst] = f2bf(kv - bf2f(kh));
}

// ================= fused_attn =================
// WRITE_E=1: pass A only; e-tiles (bf16, already in Psh for PV) are copied coalesced to
// ebuf; invS stored to global; attn produced by attn_norm. WRITE_E=0: round-8 behavior
// (pass B recomputes e and writes normalized fp32 attn).
template <bool WRITE_E>
__global__ __launch_bounds__(256) void fused_attn(const unsigned short* __restrict__ Qhi,
                                                  const unsigned short* __restrict__ Qlo,
                                                  const unsigned short* __restrict__ Khi,
                                                  const unsigned short* __restrict__ Klo,
                                                  const unsigned short* __restrict__ LVbT,
                                                  const float* __restrict__ qn2,
                                                  const float* __restrict__ kn2,
                                                  float* __restrict__ attn,
                                                  float* __restrict__ outcat,
                                                  unsigned short* __restrict__ ebuf,
                                                  float* __restrict__ invSg) {
    __shared__ unsigned short KshH[64 * 64], KshL[64 * 64], LVsh[64 * 64], Psh[32 * 64];
    __shared__ float kn2s[2048];
    __shared__ float qn2s[32];
    __shared__ float rsL[4][32], nsL[4][32];
    __shared__ float invSL[32], coefL[32];

    // XCD-pair mapping: XCD x works bh {2x, 2x+1} (K/LV set ~1.5 MB fits per-XCD L2)
    const int wgid = blockIdx.x;
    const int x = wgid & 7, bq_ = wgid >> 3;
    const int bh = 2 * x + (bq_ >> 6);
    const int i0 = (bq_ & 63) * 32;
    const int b = bh >> 3, h = bh & 7;
    const int tid = threadIdx.x;
    const int w = tid >> 6, l = tid & 63;
    const int lr = l & 15, lh = l >> 4;
    const int srj = tid >> 2;            // staging row (j or dk) 0..63
    const int skk = (tid & 3) * 16;      // staging k base
    const size_t kvbase = ((size_t)(bh << 11)) << 6;     // K planes base (shorts)
    const size_t lvbase = ((size_t)bh) << 17;            // LVbT base

    {
        const float* src = kn2 + (bh << 11) + tid * 8;
        *(float4*)&kn2s[tid * 8]     = *(const float4*)src;
        *(float4*)&kn2s[tid * 8 + 4] = *(const float4*)(src + 4);
        if (tid < 32) qn2s[tid] = qn2[(bh << 11) + i0 + tid];
    }
    bf16x8 qah[2][2], qal[2][2];
#pragma unroll
    for (int fm = 0; fm < 2; ++fm)
#pragma unroll
        for (int ks = 0; ks < 2; ++ks) {
            const size_t a = ((size_t)(bh << 11) + i0 + fm * 16 + lr) * 64 + (ks * 4 + lh) * 8;
            qah[fm][ks] = *(const bf16x8*)&Qhi[a];
            qal[fm][ks] = *(const bf16x8*)&Qlo[a];
        }

    const int ga = (((skk >> 3) ^ (srj & 7)) << 3);
    const int gb = ((((skk >> 3) + 1) ^ (srj & 7)) << 3);
    const int jc = w * 16 + lr;          // this wave's col (j in QK n-frag / dk in PV)
    uint4 pA0, pA1, pB0, pB1, pC0, pC1;
    {
        const unsigned short* kh = Khi + kvbase + (size_t)srj * 64 + skk;
        const unsigned short* kl = Klo + kvbase + (size_t)srj * 64 + skk;
        const unsigned short* lv = LVbT + lvbase + (size_t)srj * 2048 + skk;
        pA0 = *(const uint4*)kh; pA1 = *(const uint4*)(kh + 8);
        pB0 = *(const uint4*)kl; pB1 = *(const uint4*)(kl + 8);
        pC0 = *(const uint4*)lv; pC1 = *(const uint4*)(lv + 8);
    }

    f32x4 pvacc[2];
    pvacc[0] = (f32x4){0.f, 0.f, 0.f, 0.f};
    pvacc[1] = (f32x4){0.f, 0.f, 0.f, 0.f};
    float rsp[2][4] = {};

    // ---------------- pass A ----------------
    for (int t = 0; t < 32; ++t) {
        const int j0 = t * 64;
        if (t) __syncthreads();
        *(uint4*)&KshH[srj * 64 + ga] = pA0; *(uint4*)&KshH[srj * 64 + gb] = pA1;
        *(uint4*)&KshL[srj * 64 + ga] = pB0; *(uint4*)&KshL[srj * 64 + gb] = pB1;
        *(uint4*)&LVsh[srj * 64 + ga] = pC0; *(uint4*)&LVsh[srj * 64 + gb] = pC1;
        if (t < 31) {
            const unsigned short* kh = Khi + kvbase + (size_t)(j0 + 64 + srj) * 64 + skk;
            const unsigned short* kl = Klo + kvbase + (size_t)(j0 + 64 + srj) * 64 + skk;
            const unsigned short* lv = LVbT + lvbase + (size_t)srj * 2048 + j0 + 64 + skk;
            pA0 = *(const uint4*)kh; pA1 = *(const uint4*)(kh + 8);
            pB0 = *(const uint4*)kl; pB1 = *(const uint4*)(kl + 8);
            pC0 = *(const uint4*)lv; pC1 = *(const uint4*)(lv + 8);
        }
        __syncthreads();
        f32x4 sacc[2];
        sacc[0] = (f32x4){0.f, 0.f, 0.f, 0.f};
        sacc[1] = (f32x4){0.f, 0.f, 0.f, 0.f};
#pragma unroll
        for (int ks = 0; ks < 2; ++ks) {
            const int kb = ks * 4 + lh;
            const int boff = jc * 64 + ((kb ^ (jc & 7)) << 3);
            bf16x8 bh8 = *(const bf16x8*)&KshH[boff];
            bf16x8 bl8 = *(const bf16x8*)&KshL[boff];
#pragma unroll
            for (int fm = 0; fm < 2; ++fm) {
                sacc[fm] = __builtin_amdgcn_mfma_f32_16x16x32_bf16(qah[fm][ks], bh8, sacc[fm], 0, 0, 0);
                sacc[fm] = __builtin_amdgcn_mfma_f32_16x16x32_bf16(qal[fm][ks], bh8, sacc[fm], 0, 0, 0);
                sacc[fm] = __builtin_amdgcn_mfma_f32_16x16x32_bf16(qah[fm][ks], bl8, sacc[fm], 0, 0, 0);
            }
        }
        const float y2 = kn2s[j0 + jc];
        const int pg = jc >> 3, pw = jc & 7;
#pragma unroll
        for (int fm = 0; fm < 2; ++fm)
#pragma unroll
            for (int r = 0; r < 4; ++r) {
                const int row = fm * 16 + lh * 4 + r;
                float xy = sacc[fm][r];
                float x2 = qn2s[row];
                float A_ = 1.f - 2.f * xy + y2;
                float Bc = 1.f - x2;
                float num2 = A_ * A_ * x2 + Bc * Bc * y2 - 2.f * A_ * Bc * xy;
                float den  = fmaxf(1.f - 2.f * xy + x2 * y2, 1e-15f);
                float sn   = __builtin_amdgcn_sqrtf(fmaxf(num2, 0.f));
                float dm   = den - sn;
                dm = fmaxf(dm, (den + sn) * 5e-8f);
                float rr = (den + sn) * __builtin_amdgcn_rcpf(dm);
                float e = __builtin_amdgcn_exp2f(-0.125f * __builtin_amdgcn_logf(rr));
                rsp[fm][r] += e;
                Psh[row * 64 + ((pg ^ (row & 7)) << 3) + pw] = f2bf(e);
            }
        __syncthreads();
#pragma unroll
        for (int ks = 0; ks < 2; ++ks) {
            const int kb = ks * 4 + lh;
            bf16x8 bv8 = *(const bf16x8*)&LVsh[jc * 64 + ((kb ^ (jc & 7)) << 3)];
#pragma unroll
            for (int fm = 0; fm < 2; ++fm) {
                const int prow = fm * 16 + lr;
                bf16x8 pa = *(const bf16x8*)&Psh[prow * 64 + ((kb ^ (prow & 7)) << 3)];
                pvacc[fm] = __builtin_amdgcn_mfma_f32_16x16x32_bf16(pa, bv8, pvacc[fm], 0, 0, 0);
            }
        }
        if constexpr (WRITE_E) {
            // coalesced e-tile flush: thread (prow = tid>>3, g = tid&7) moves 8 bf16
            const int prow = tid >> 3, g = tid & 7;
            uint4 ev = *(const uint4*)&Psh[prow * 64 + ((g ^ (prow & 7)) << 3)];
            *(uint4*)(ebuf + ((size_t)(bh << 11) + i0 + prow) * kS + j0 + g * 8) = ev;
        }
    }
    __syncthreads();
#pragma unroll
    for (int fm = 0; fm < 2; ++fm)
#pragma unroll
        for (int r = 0; r < 4; ++r) {
            float v = rsp[fm][r];
            v += __shfl_xor(v, 1, 64); v += __shfl_xor(v, 2, 64);
            v += __shfl_xor(v, 4, 64); v += __shfl_xor(v, 8, 64);
            rsp[fm][r] = v;
        }
    if (lr == 0) {
#pragma unroll
        for (int fm = 0; fm < 2; ++fm)
#pragma unroll
            for (int r = 0; r < 4; ++r) rsL[w][fm * 16 + lh * 4 + r] = rsp[fm][r];
    }
    __syncthreads();
    if (tid < 32) {
        float is = 1.f / (rsL[0][tid] + rsL[1][tid] + rsL[2][tid] + rsL[3][tid]);
        invSL[tid] = is;
        if constexpr (WRITE_E) invSg[(bh << 11) + i0 + tid] = is;
    }
    __syncthreads();
    float mval[2][4];
#pragma unroll
    for (int fm = 0; fm < 2; ++fm)
#pragma unroll
        for (int r = 0; r < 4; ++r) {
            const int row = fm * 16 + lh * 4 + r;
            float m = pvacc[fm][r] * invSL[row];
            mval[fm][r] = m;
            float ns = m * m;
            ns += __shfl_xor(ns, 1, 64); ns += __shfl_xor(ns, 2, 64);
            ns += __shfl_xor(ns, 4, 64); ns += __shfl_xor(ns, 8, 64);
            if (lr == 0) nsL[w][row] = ns;
        }
    __syncthreads();
    if (tid < 32) {
        float ns = nsL[0][tid] + nsL[1][tid] + nsL[2][tid] + nsL[3][tid];
        float un = sqrtf(fmaxf(ns, 1e-15f));
        coefL[tid] = tanhf(un) / un;
    }
    __syncthreads();
#pragma unroll
    for (int fm = 0; fm < 2; ++fm)
#pragma unroll
        for (int r = 0; r < 4; ++r) {
            const int row = fm * 16 + lh * 4 + r;
            outcat[(size_t)(b * kS + i0 + row) * kD + h * kDK + jc] = mval[fm][r] * coefL[row];
        }

    if constexpr (!WRITE_E) {
        // ---------------- pass B: recompute e, write normalized attn once ----------------
        __shared__ float epl[32 * 68];
        {
            const unsigned short* kh = Khi + kvbase + (size_t)srj * 64 + skk;
            const unsigned short* kl = Klo + kvbase + (size_t)srj * 64 + skk;
            pA0 = *(const uint4*)kh; pA1 = *(const uint4*)(kh + 8);
            pB0 = *(const uint4*)kl; pB1 = *(const uint4*)(kl + 8);
        }
        for (int t = 0; t < 32; ++t) {
            const int j0 = t * 64;
            __syncthreads();
            *(uint4*)&KshH[srj * 64 + ga] = pA0; *(uint4*)&KshH[srj * 64 + gb] = pA1;
            *(uint4*)&KshL[srj * 64 + ga] = pB0; *(uint4*)&KshL[srj * 64 + gb] = pB1;
            if (t < 31) {
                const unsigned short* kh = Khi + kvbase + (size_t)(j0 + 64 + srj) * 64 + skk;
                const unsigned short* kl = Klo + kvbase + (size_t)(j0 + 64 + srj) * 64 + skk;
                pA0 = *(const uint4*)kh; pA1 = *(const uint4*)(kh + 8);
                pB0 = *(const uint4*)kl; pB1 = *(const uint4*)(kl + 8);
            }
            __syncthreads();
            f32x4 sacc[2];
            sacc[0] = (f32x4){0.f, 0.f, 0.f, 0.f};
            sacc[1] = (f32x4){0.f, 0.f, 0.f, 0.f};
#pragma unroll
            for (int ks = 0; ks < 2; ++ks) {
                const int kb = ks * 4 + lh;
                const int boff = jc * 64 + ((kb ^ (jc & 7)) << 3);
                bf16x8 bh8 = *(const bf16x8*)&KshH[boff];
                bf16x8 bl8 = *(const bf16x8*)&KshL[boff];
#pragma unroll
                for (int fm = 0; fm < 2; ++fm) {
                    sacc[fm] = __builtin_amdgcn_mfma_f32_16x16x32_bf16(qah[fm][ks], bh8, sacc[fm], 0, 0, 0);
                    sacc[fm] = __builtin_amdgcn_mfma_f32_16x16x32_bf16(qal[fm][ks], bh8, sacc[fm], 0, 0, 0);
                    sacc[fm] = __builtin_amdgcn_mfma_f32_16x16x32_bf16(qah[fm][ks], bl8, sacc[fm], 0, 0, 0);
                }
            }
            const float y2 = kn2s[j0 + jc];
#pragma unroll
            for (int fm = 0; fm < 2; ++fm)
#pragma unroll
                for (int r = 0; r < 4; ++r) {
                    const int row = fm * 16 + lh * 4 + r;
                    float xy = sacc[fm][r];
                    float x2 = qn2s[row];
                    float A_ = 1.f - 2.f * xy + y2;
                    float Bc = 1.f - x2;
                    float num2 = A_ * A_ * x2 + Bc * Bc * y2 - 2.f * A_ * Bc * xy;
                    float den  = fmaxf(1.f - 2.f * xy + x2 * y2, 1e-15f);
                    float sn   = __builtin_amdgcn_sqrtf(fmaxf(num2, 0.f));
                    float dm   = den - sn;
                    dm = fmaxf(dm, (den + sn) * 5e-8f);
                    float rr = (den + sn) * __builtin_amdgcn_rcpf(dm);
                    float e = __builtin_amdgcn_exp2f(-0.125f * __builtin_amdgcn_logf(rr));
                    epl[row * 68 + jc] = e * invSL[row];
                }
            __syncthreads();
            const int row = tid >> 3, c8 = (tid & 7) * 8;
            float4 v0 = *(const float4*)&epl[row * 68 + c8];
            float4 v1 = *(const float4*)&epl[row * 68 + c8 + 4];
            float* dst = attn + ((size_t)(bh << 11) + i0 + row) * kS + j0 + c8;
            *(float4*)dst = v0;
            *(float4*)(dst + 4) = v1;
        }
    }
}

// ------- attn_norm: attn[row][j] = bf2f(ebuf[row][j]) * invS[row] (streaming) -------
__global__ __launch_bounds__(256) void attn_norm(const unsigned short* __restrict__ ebuf,
                                                 const float* __restrict__ invSg,
                                                 float* __restrict__ attn) {
    const size_t gid = (size_t)blockIdx.x * 256 + threadIdx.x;   // 8,388,608 threads
    const size_t row = gid >> 8;
    const int col8 = (int)(gid & 255) * 8;
    uint4 v = *(const uint4*)(ebuf + row * kS + col8);
    const float is = invSg[row];
    float o[8];
    o[0] = __uint_as_float(v.x << 16) * is;
    o[1] = __uint_as_float(v.x & 0xFFFF0000u) * is;
    o[2] = __uint_as_float(v.y << 16) * is;
    o[3] = __uint_as_float(v.y & 0xFFFF0000u) * is;
    o[4] = __uint_as_float(v.z << 16) * is;
    o[5] = __uint_as_float(v.z & 0xFFFF0000u) * is;
    o[6] = __uint_as_float(v.w << 16) * is;
    o[7] = __uint_as_float(v.w & 0xFFFF0000u) * is;
    float* dst = attn + row * kS + col8;
    *(float4*)dst       = make_float4(o[0], o[1], o[2], o[3]);
    *(float4*)(dst + 4) = make_float4(o[4], o[5], o[6], o[7]);
}

} // namespace

extern "C" void kernel_launch(void* const* d_in, const int* in_sizes, int n_in,
                              void* d_out, int out_size, void* d_ws, size_t ws_size,
                              hipStream_t stream) {
    const float* q  = (const float*)d_in[0];
    const float* k  = (const float*)d_in[1];
    const float* v  = (const float*)d_in[2];
    const float* Wq = (const float*)d_in[3];
    const float* bq = (const float*)d_in[4];
    const float* Wk = (const float*)d_in[5];
    const float* bk = (const float*)d_in[6];
    const float* Wv = (const float*)d_in[7];
    const float* bv = (const float*)d_in[8];
    const float* Wo = (const float*)d_in[9];
    const float* bo = (const float*)d_in[10];

    float* out  = (float*)d_out;
    float* attn = out + (size_t)kM * kD;   // out (2M floats), then attn (64M floats)

    constexpr size_t NBUF = (size_t)kM * kD; // 2,097,152 floats (8 MB)
    float* ws  = (float*)d_ws;
    float* A0  = ws;              // Qp
    float* A1  = ws + NBUF;       // Kp -> later outcat
    float* A2  = ws + 2 * NBUF;   // Vp -> Qhi/Qlo bf16 -> mx for final gemm
    float* A3  = ws + 3 * NBUF;   // mx scratch -> LVbT (4MB)
    float* qn2 = ws + 4 * NBUF;                       // 32768 floats
    float* kn2 = qn2 + (size_t)kBH * kS;              // 32768 floats
    float* invSg = kn2 + (size_t)kBH * kS;            // 32768 floats
    // ebuf (bf16 e, 134 MB) right after: only used if ws is large enough
    const size_t ebuf_off_bytes = (4 * NBUF + 3 * (size_t)kBH * kS) * sizeof(float);
    unsigned short* ebuf = (unsigned short*)((char*)d_ws + ebuf_off_bytes);
    const size_t ebuf_bytes = (size_t)kBH * kS * kS * sizeof(unsigned short); // 134,217,728
    const bool fast = ws_size >= ebuf_off_bytes + ebuf_bytes;

    constexpr size_t HP = (size_t)kBH * kS * kDK;   // 2,097,152 ushorts = 4 MB per plane
    unsigned short* Qhi = (unsigned short*)A2;
    unsigned short* Qlo = Qhi + HP;
    unsigned short* Khi = (unsigned short*)out;     // out region free until final rowops
    unsigned short* Klo = Khi + HP;
    unsigned short* LVbT = (unsigned short*)A3;     // [bh][64][2048] bf16 (4 MB)

    dim3 gg(kM / 64, kD / 64);

    gemm_mfma<<<gg, 256, 0, stream>>>(q, Wq, A3);
    rowops<<<kM, 256, 0, stream>>>(q, A3, bq, A0);
    gemm_mfma<<<gg, 256, 0, stream>>>(k, Wk, A3);
    rowops<<<kM, 256, 0, stream>>>(k, A3, bk, A1);
    gemm_mfma<<<gg, 256, 0, stream>>>(v, Wv, A3);
    rowops<<<kM, 256, 0, stream>>>(v, A3, bv, A2);

    prep2<<<kBH * 32, 256, 0, stream>>>(A0, A1, A2, qn2, kn2, LVbT);

    split_qk<<<(kBH * kS) / 4, 256, 0, stream>>>(A0, A1, Qhi, Qlo, Khi, Klo);

    if (fast) {
        fused_attn<true><<<kBH * (kS / 32), 256, 0, stream>>>(
            Qhi, Qlo, Khi, Klo, LVbT, qn2, kn2, attn, A1, ebuf, invSg);
        attn_norm<<<(kBH * kS * kS / 8) / 256, 256, 0, stream>>>(ebuf, invSg, attn);
    } else {
        fused_attn<false><<<kBH * (kS / 32), 256, 0, stream>>>(
            Qhi, Qlo, Khi, Klo, LVbT, qn2, kn2, attn, A1, ebuf, invSg);
    }

    gemm_mfma<<<gg, 256, 0, stream>>>(A1, Wo, A2);
    rowops<<<kM, 256, 0, stream>>>(A1, A2, bo, out);
}

// Round 10
// 298.275 us; speedup vs baseline: 1.0192x; 1.0192x over previous
//
#include <hip/hip_runtime.h>
#include <math.h>

namespace {

constexpr int kB  = 2;
constexpr int kS  = 2048;
constexpr int kD  = 512;
constexpr int kH  = 8;
constexpr int kDK = 64;
constexpr int kM  = kB * kS;   // 4096 rows
constexpr int kBH = kB * kH;   // 16

typedef __attribute__((ext_vector_type(8))) short bf16x8;
typedef __attribute__((ext_vector_type(4))) float f32x4;

__device__ __forceinline__ float wave_sum64(float v) {
#pragma unroll
    for (int o = 32; o > 0; o >>= 1) v += __shfl_xor(v, o, 64);
    return v;
}

__device__ __forceinline__ unsigned short f2bf(float f) {
    unsigned u = __float_as_uint(f);
    unsigned r = (u + 0x7FFF + ((u >> 16) & 1)) >> 16;   // round-to-nearest-even
    return (unsigned short)r;
}
__device__ __forceinline__ float bf2f(unsigned short h) {
    return __uint_as_float(((unsigned)h) << 16);
}

#define MAXN_F  ((float)(1.0 - 1e-5))
#define ACLIP_F ((float)(1.0 - 1e-7))

// ---- GEMM via split-bf16 MFMA: Y(4096x512) = X(4096x512) @ W(512x512)^T ----
__global__ __launch_bounds__(256) void gemm_mfma(const float* __restrict__ X,
                                                 const float* __restrict__ W,
                                                 float* __restrict__ Y) {
    __shared__ unsigned short Ah[64 * 64], Al[64 * 64], Bh[64 * 64], Bl[64 * 64];
    const int m0 = blockIdx.x * 64;
    const int n0 = blockIdx.y * 64;
    const int tid = threadIdx.x;
    const int w = tid >> 6, l = tid & 63;
    const int lr = l & 15, lh = l >> 4;
    const int sr = tid >> 2;          // staging row 0..63
    const int sk = (tid & 3) * 16;    // staging k base (16 elems/thread)
    float4 xr[4], wr[4];
#pragma unroll
    for (int i = 0; i < 4; ++i) {
        xr[i] = *(const float4*)(X + (size_t)(m0 + sr) * 512 + sk + i * 4);
        wr[i] = *(const float4*)(W + (size_t)(n0 + sr) * 512 + sk + i * 4);
    }
    f32x4 acc[4];
#pragma unroll
    for (int j = 0; j < 4; ++j) acc[j] = (f32x4){0.f, 0.f, 0.f, 0.f};

    for (int c = 0; c < 8; ++c) {
        if (c) __syncthreads();       // previous MFMA done reading LDS
        {
            unsigned hx[8], lx[8], hw_[8], lw_[8];
#pragma unroll
            for (int t = 0; t < 8; ++t) {
                float e0 = ((const float*)&xr[t >> 1])[(t & 1) * 2 + 0];
                float e1 = ((const float*)&xr[t >> 1])[(t & 1) * 2 + 1];
                unsigned short h0 = f2bf(e0), h1 = f2bf(e1);
                hx[t] = (unsigned)h0 | ((unsigned)h1 << 16);
                lx[t] = (unsigned)f2bf(e0 - bf2f(h0)) | ((unsigned)f2bf(e1 - bf2f(h1)) << 16);
                float f0 = ((const float*)&wr[t >> 1])[(t & 1) * 2 + 0];
                float f1 = ((const float*)&wr[t >> 1])[(t & 1) * 2 + 1];
                unsigned short g0 = f2bf(f0), g1 = f2bf(f1);
                hw_[t] = (unsigned)g0 | ((unsigned)g1 << 16);
                lw_[t] = (unsigned)f2bf(f0 - bf2f(g0)) | ((unsigned)f2bf(f1 - bf2f(g1)) << 16);
            }
            const int ga = (sk >> 3) ^ (sr & 7);
            const int gb = ((sk >> 3) + 1) ^ (sr & 7);
            *(uint4*)&Ah[sr * 64 + ga * 8] = make_uint4(hx[0], hx[1], hx[2], hx[3]);
            *(uint4*)&Ah[sr * 64 + gb * 8] = make_uint4(hx[4], hx[5], hx[6], hx[7]);
            *(uint4*)&Al[sr * 64 + ga * 8] = make_uint4(lx[0], lx[1], lx[2], lx[3]);
            *(uint4*)&Al[sr * 64 + gb * 8] = make_uint4(lx[4], lx[5], lx[6], lx[7]);
            *(uint4*)&Bh[sr * 64 + ga * 8] = make_uint4(hw_[0], hw_[1], hw_[2], hw_[3]);
            *(uint4*)&Bh[sr * 64 + gb * 8] = make_uint4(hw_[4], hw_[5], hw_[6], hw_[7]);
            *(uint4*)&Bl[sr * 64 + ga * 8] = make_uint4(lw_[0], lw_[1], lw_[2], lw_[3]);
            *(uint4*)&Bl[sr * 64 + gb * 8] = make_uint4(lw_[4], lw_[5], lw_[6], lw_[7]);
        }
        if (c < 7) {
            const int k1 = (c + 1) * 64;
#pragma unroll
            for (int i = 0; i < 4; ++i) {
                xr[i] = *(const float4*)(X + (size_t)(m0 + sr) * 512 + k1 + sk + i * 4);
                wr[i] = *(const float4*)(W + (size_t)(n0 + sr) * 512 + k1 + sk + i * 4);
            }
        }
        __syncthreads();
#pragma unroll
        for (int ks = 0; ks < 2; ++ks) {
            const int kb = ks * 4 + lh;
            const int row = w * 16 + lr;
            const int aoff = row * 64 + ((kb ^ (row & 7)) << 3);
            bf16x8 ah = *(const bf16x8*)&Ah[aoff];
            bf16x8 al = *(const bf16x8*)&Al[aoff];
#pragma unroll
            for (int fn = 0; fn < 4; ++fn) {
                const int col = fn * 16 + lr;
                const int boff = col * 64 + ((kb ^ (col & 7)) << 3);
                bf16x8 bh8 = *(const bf16x8*)&Bh[boff];
                bf16x8 bl8 = *(const bf16x8*)&Bl[boff];
                acc[fn] = __builtin_amdgcn_mfma_f32_16x16x32_bf16(ah, bh8, acc[fn], 0, 0, 0);
                acc[fn] = __builtin_amdgcn_mfma_f32_16x16x32_bf16(al, bh8, acc[fn], 0, 0, 0);
                acc[fn] = __builtin_amdgcn_mfma_f32_16x16x32_bf16(ah, bl8, acc[fn], 0, 0, 0);
            }
        }
    }
#pragma unroll
    for (int fn = 0; fn < 4; ++fn)
#pragma unroll
        for (int r = 0; r < 4; ++r)
            Y[(size_t)(m0 + w * 16 + lh * 4 + r) * 512 + n0 + fn * 16 + lr] = acc[fn][r];
}

// --------- mobius_linear tail: res=matvec scale; mobius_add(res,b); project ---------
__global__ __launch_bounds__(256) void rowops(const float* __restrict__ X,
                                              const float* __restrict__ MX,
                                              const float* __restrict__ bvec,
                                              float* __restrict__ out) {
    __shared__ float4 red4[4];
    __shared__ float red1[4];
    const int row = blockIdx.x;
    const int tid = threadIdx.x;
    const float2 xv = ((const float2*)(X + (size_t)row * kD))[tid];
    const float2 mv = ((const float2*)(MX + (size_t)row * kD))[tid];
    const float2 bv = ((const float2*)bvec)[tid];
    float sx  = fmaf(xv.x, xv.x, xv.y * xv.y);
    float sm  = fmaf(mv.x, mv.x, mv.y * mv.y);
    float smb = fmaf(mv.x, bv.x, mv.y * bv.y);
    float sb  = fmaf(bv.x, bv.x, bv.y * bv.y);
#pragma unroll
    for (int o = 32; o > 0; o >>= 1) {
        sx  += __shfl_xor(sx, o, 64);
        sm  += __shfl_xor(sm, o, 64);
        smb += __shfl_xor(smb, o, 64);
        sb  += __shfl_xor(sb, o, 64);
    }
    if ((tid & 63) == 0) red4[tid >> 6] = make_float4(sx, sm, smb, sb);
    __syncthreads();
    {
        float4 r0 = red4[0], r1 = red4[1], r2 = red4[2], r3 = red4[3];
        sx  = r0.x + r1.x + r2.x + r3.x;
        sm  = r0.y + r1.y + r2.y + r3.y;
        smb = r0.z + r1.z + r2.z + r3.z;
        sb  = r0.w + r1.w + r2.w + r3.w;
    }
    float xn  = sqrtf(fmaxf(sx, 1e-15f));
    float mxn = sqrtf(fmaxf(sm, 1e-15f));
    float xc  = fminf(xn, ACLIP_F);
    float at  = 0.5f * logf((1.f + xc) / (1.f - xc));       // artanh(xn)
    float sc  = tanhf(mxn / xn * at) / mxn;                 // res = sc * mx
    if (sm == 0.f) sc = 0.f;                                // all(mx==0) branch
    float x2 = sc * sc * sm;
    float xy = sc * smb;
    float y2 = sb;
    float c1 = 1.f + 2.f * xy + y2;
    float c2 = 1.f - x2;
    float den = fmaxf(1.f + 2.f * xy + x2 * y2, 1e-15f);
    float idn = 1.f / den;
    float ux = (c1 * sc * mv.x + c2 * bv.x) * idn;
    float uy = (c1 * sc * mv.y + c2 * bv.y) * idn;
    float su = wave_sum64(fmaf(ux, ux, uy * uy));
    if ((tid & 63) == 0) red1[tid >> 6] = su;
    __syncthreads();
    su = (red1[0] + red1[1]) + (red1[2] + red1[3]);
    float n = sqrtf(fmaxf(su, 1e-15f));
    float f = (n > MAXN_F) ? (MAXN_F / n) : 1.f;
    ((float2*)(out + (size_t)row * kD))[tid] = make_float2(ux * f, uy * f);
}

// ---- prep2: per-head-row |q|^2,|k|^2 + LVbT[bh][n][k] = bf16(logmap0(V_head))^T ----
__global__ __launch_bounds__(256) void prep2(const float* __restrict__ Qp,
                                             const float* __restrict__ Kp,
                                             const float* __restrict__ Vp,
                                             float* __restrict__ qn2,
                                             float* __restrict__ kn2,
                                             unsigned short* __restrict__ LVbT) {
    __shared__ unsigned short T[64][66];   // [n][s_local], 66 -> 2-way banks (free)
    const int bh = blockIdx.x >> 5;
    const int k0 = (blockIdx.x & 31) * 64;
    const int b = bh >> 3, h = bh & 7;
    const int w = threadIdx.x >> 6, l = threadIdx.x & 63;
#pragma unroll 4
    for (int i = 0; i < 16; ++i) {
        const int s = k0 + w * 16 + i;
        const size_t src = (size_t)(b * kS + s) * kD + h * kDK + l;
        float qv = Qp[src], kv = Kp[src], vv = Vp[src];
        float sq = wave_sum64(qv * qv);
        float sk = wave_sum64(kv * kv);
        float sv = wave_sum64(vv * vv);
        if (l == 0) { qn2[(bh << 11) + s] = sq; kn2[(bh << 11) + s] = sk; }
        float yn = sqrtf(fmaxf(sv, 1e-15f));
        float yc = fminf(yn, ACLIP_F);
        float coef = 0.5f * logf((1.f + yc) / (1.f - yc)) / yn;
        T[l][w * 16 + i] = f2bf(vv * coef);
    }
    __syncthreads();
    const int n = threadIdx.x >> 2, kk = (threadIdx.x & 3) * 16;
    const unsigned int* Tr = (const unsigned int*)&T[n][kk];
    unsigned int u0 = Tr[0], u1 = Tr[1], u2 = Tr[2], u3 = Tr[3];
    unsigned int u4 = Tr[4], u5 = Tr[5], u6 = Tr[6], u7 = Tr[7];
    unsigned short* dst = LVbT + (((size_t)(bh * 64 + n)) << 11) + k0 + kk;
    *(uint4*)dst = make_uint4(u0, u1, u2, u3);
    *(uint4*)(dst + 8) = make_uint4(u4, u5, u6, u7);
}

// ---- split_qk: Q,K head-gathered -> hi/lo bf16 planes [bh][s][64] (split-precision) ----
__global__ __launch_bounds__(256) void split_qk(const float* __restrict__ Qp,
                                                const float* __restrict__ Kp,
                                                unsigned short* __restrict__ Qhi,
                                                unsigned short* __restrict__ Qlo,
                                                unsigned short* __restrict__ Khi,
                                                unsigned short* __restrict__ Klo) {
    const int gid  = blockIdx.x * 4 + (threadIdx.x >> 6);
    const int lane = threadIdx.x & 63;
    const int bh = gid >> 11, s = gid & 2047;
    const int b = bh >> 3, h = bh & 7;
    const size_t src = (size_t)(b * kS + s) * kD + h * kDK + lane;
    const size_t dst = ((size_t)gid << 6) + lane;
    float qv = Qp[src];
    unsigned short qh = f2bf(qv);
    Qhi[dst] = qh;
    Qlo[dst] = f2bf(qv - bf2f(qh));
    float kv = Kp[src];
    unsigned short kh = f2bf(kv);
    Khi[dst] = kh;
    Klo[dst] = f2bf(kv - bf2f(kh));
}

// ================= fused_attn =================
// Pass A only. Per 64-col tile: split-bf16 QK MFMA -> exp epilogue -> rowsum partials +
// unnormalized PV MFMA. The bf16 e-tile (already in Psh for PV) is flushed coalesced to
// the FIRST HALF of each attn row (attn row = 8KB fp32; e occupies its first 4KB as
// bf16). invS per row stored to ws. attn_norm later expands each row in place.
__global__ __launch_bounds__(256) void fused_attn(const unsigned short* __restrict__ Qhi,
                                                  const unsigned short* __restrict__ Qlo,
                                                  const unsigned short* __restrict__ Khi,
                                                  const unsigned short* __restrict__ Klo,
                                                  const unsigned short* __restrict__ LVbT,
                                                  const float* __restrict__ qn2,
                                                  const float* __restrict__ kn2,
                                                  unsigned short* __restrict__ eattn,
                                                  float* __restrict__ outcat,
                                                  float* __restrict__ invSg) {
    __shared__ unsigned short KshH[64 * 64], KshL[64 * 64], LVsh[64 * 64], Psh[32 * 64];
    __shared__ float kn2s[2048];
    __shared__ float qn2s[32];
    __shared__ float rsL[4][32], nsL[4][32];
    __shared__ float invSL[32], coefL[32];

    // XCD-pair mapping: XCD x works bh {2x, 2x+1} (K/LV set ~1.5 MB fits per-XCD L2)
    const int wgid = blockIdx.x;
    const int x = wgid & 7, bq_ = wgid >> 3;
    const int bh = 2 * x + (bq_ >> 6);
    const int i0 = (bq_ & 63) * 32;
    const int b = bh >> 3, h = bh & 7;
    const int tid = threadIdx.x;
    const int w = tid >> 6, l = tid & 63;
    const int lr = l & 15, lh = l >> 4;
    const int srj = tid >> 2;            // staging row (j or dk) 0..63
    const int skk = (tid & 3) * 16;      // staging k base
    const size_t kvbase = ((size_t)(bh << 11)) << 6;     // K planes base (shorts)
    const size_t lvbase = ((size_t)bh) << 17;            // LVbT base

    {
        const float* src = kn2 + (bh << 11) + tid * 8;
        *(float4*)&kn2s[tid * 8]     = *(const float4*)src;
        *(float4*)&kn2s[tid * 8 + 4] = *(const float4*)(src + 4);
        if (tid < 32) qn2s[tid] = qn2[(bh << 11) + i0 + tid];
    }
    bf16x8 qah[2][2], qal[2][2];
#pragma unroll
    for (int fm = 0; fm < 2; ++fm)
#pragma unroll
        for (int ks = 0; ks < 2; ++ks) {
            const size_t a = ((size_t)(bh << 11) + i0 + fm * 16 + lr) * 64 + (ks * 4 + lh) * 8;
            qah[fm][ks] = *(const bf16x8*)&Qhi[a];
            qal[fm][ks] = *(const bf16x8*)&Qlo[a];
        }

    const int ga = (((skk >> 3) ^ (srj & 7)) << 3);
    const int gb = ((((skk >> 3) + 1) ^ (srj & 7)) << 3);
    const int jc = w * 16 + lr;          // this wave's col (j in QK n-frag / dk in PV)
    uint4 pA0, pA1, pB0, pB1, pC0, pC1;
    {
        const unsigned short* kh = Khi + kvbase + (size_t)srj * 64 + skk;
        const unsigned short* kl = Klo + kvbase + (size_t)srj * 64 + skk;
        const unsigned short* lv = LVbT + lvbase + (size_t)srj * 2048 + skk;
        pA0 = *(const uint4*)kh; pA1 = *(const uint4*)(kh + 8);
        pB0 = *(const uint4*)kl; pB1 = *(const uint4*)(kl + 8);
        pC0 = *(const uint4*)lv; pC1 = *(const uint4*)(lv + 8);
    }

    f32x4 pvacc[2];
    pvacc[0] = (f32x4){0.f, 0.f, 0.f, 0.f};
    pvacc[1] = (f32x4){0.f, 0.f, 0.f, 0.f};
    float rsp[2][4] = {};

    for (int t = 0; t < 32; ++t) {
        const int j0 = t * 64;
        if (t) __syncthreads();
        *(uint4*)&KshH[srj * 64 + ga] = pA0; *(uint4*)&KshH[srj * 64 + gb] = pA1;
        *(uint4*)&KshL[srj * 64 + ga] = pB0; *(uint4*)&KshL[srj * 64 + gb] = pB1;
        *(uint4*)&LVsh[srj * 64 + ga] = pC0; *(uint4*)&LVsh[srj * 64 + gb] = pC1;
        if (t < 31) {
            const unsigned short* kh = Khi + kvbase + (size_t)(j0 + 64 + srj) * 64 + skk;
            const unsigned short* kl = Klo + kvbase + (size_t)(j0 + 64 + srj) * 64 + skk;
            const unsigned short* lv = LVbT + lvbase + (size_t)srj * 2048 + j0 + 64 + skk;
            pA0 = *(const uint4*)kh; pA1 = *(const uint4*)(kh + 8);
            pB0 = *(const uint4*)kl; pB1 = *(const uint4*)(kl + 8);
            pC0 = *(const uint4*)lv; pC1 = *(const uint4*)(lv + 8);
        }
        __syncthreads();
        f32x4 sacc[2];
        sacc[0] = (f32x4){0.f, 0.f, 0.f, 0.f};
        sacc[1] = (f32x4){0.f, 0.f, 0.f, 0.f};
#pragma unroll
        for (int ks = 0; ks < 2; ++ks) {
            const int kb = ks * 4 + lh;
            const int boff = jc * 64 + ((kb ^ (jc & 7)) << 3);
            bf16x8 bh8 = *(const bf16x8*)&KshH[boff];
            bf16x8 bl8 = *(const bf16x8*)&KshL[boff];
#pragma unroll
            for (int fm = 0; fm < 2; ++fm) {
                sacc[fm] = __builtin_amdgcn_mfma_f32_16x16x32_bf16(qah[fm][ks], bh8, sacc[fm], 0, 0, 0);
                sacc[fm] = __builtin_amdgcn_mfma_f32_16x16x32_bf16(qal[fm][ks], bh8, sacc[fm], 0, 0, 0);
                sacc[fm] = __builtin_amdgcn_mfma_f32_16x16x32_bf16(qah[fm][ks], bl8, sacc[fm], 0, 0, 0);
            }
        }
        const float y2 = kn2s[j0 + jc];
        const int pg = jc >> 3, pw = jc & 7;
#pragma unroll
        for (int fm = 0; fm < 2; ++fm)
#pragma unroll
            for (int r = 0; r < 4; ++r) {
                const int row = fm * 16 + lh * 4 + r;
                float xy = sacc[fm][r];
                float x2 = qn2s[row];
                float A_ = 1.f - 2.f * xy + y2;
                float Bc = 1.f - x2;
                float num2 = A_ * A_ * x2 + Bc * Bc * y2 - 2.f * A_ * Bc * xy;
                float den  = fmaxf(1.f - 2.f * xy + x2 * y2, 1e-15f);
                float sn   = __builtin_amdgcn_sqrtf(fmaxf(num2, 0.f));
                float dm   = den - sn;
                dm = fmaxf(dm, (den + sn) * 5e-8f);
                float rr = (den + sn) * __builtin_amdgcn_rcpf(dm);
                float e = __builtin_amdgcn_exp2f(-0.125f * __builtin_amdgcn_logf(rr));
                rsp[fm][r] += e;
                Psh[row * 64 + ((pg ^ (row & 7)) << 3) + pw] = f2bf(e);
            }
        __syncthreads();
#pragma unroll
        for (int ks = 0; ks < 2; ++ks) {
            const int kb = ks * 4 + lh;
            bf16x8 bv8 = *(const bf16x8*)&LVsh[jc * 64 + ((kb ^ (jc & 7)) << 3)];
#pragma unroll
            for (int fm = 0; fm < 2; ++fm) {
                const int prow = fm * 16 + lr;
                bf16x8 pa = *(const bf16x8*)&Psh[prow * 64 + ((kb ^ (prow & 7)) << 3)];
                pvacc[fm] = __builtin_amdgcn_mfma_f32_16x16x32_bf16(pa, bv8, pvacc[fm], 0, 0, 0);
            }
        }
        // coalesced e-tile flush into the FIRST HALF of each attn row (bf16):
        // row stride in ushorts = 4096 (the row's 8KB); e[j] at ushort index j < 2048.
        {
            const int prow = tid >> 3, g = tid & 7;
            uint4 ev = *(const uint4*)&Psh[prow * 64 + ((g ^ (prow & 7)) << 3)];
            *(uint4*)(eattn + ((size_t)(bh << 11) + i0 + prow) * 4096 + j0 + g * 8) = ev;
        }
    }
    __syncthreads();
#pragma unroll
    for (int fm = 0; fm < 2; ++fm)
#pragma unroll
        for (int r = 0; r < 4; ++r) {
            float v = rsp[fm][r];
            v += __shfl_xor(v, 1, 64); v += __shfl_xor(v, 2, 64);
            v += __shfl_xor(v, 4, 64); v += __shfl_xor(v, 8, 64);
            rsp[fm][r] = v;
        }
    if (lr == 0) {
#pragma unroll
        for (int fm = 0; fm < 2; ++fm)
#pragma unroll
            for (int r = 0; r < 4; ++r) rsL[w][fm * 16 + lh * 4 + r] = rsp[fm][r];
    }
    __syncthreads();
    if (tid < 32) {
        float is = 1.f / (rsL[0][tid] + rsL[1][tid] + rsL[2][tid] + rsL[3][tid]);
        invSL[tid] = is;
        invSg[(bh << 11) + i0 + tid] = is;
    }
    __syncthreads();
    float mval[2][4];
#pragma unroll
    for (int fm = 0; fm < 2; ++fm)
#pragma unroll
        for (int r = 0; r < 4; ++r) {
            const int row = fm * 16 + lh * 4 + r;
            float m = pvacc[fm][r] * invSL[row];
            mval[fm][r] = m;
            float ns = m * m;
            ns += __shfl_xor(ns, 1, 64); ns += __shfl_xor(ns, 2, 64);
            ns += __shfl_xor(ns, 4, 64); ns += __shfl_xor(ns, 8, 64);
            if (lr == 0) nsL[w][row] = ns;
        }
    __syncthreads();
    if (tid < 32) {
        float ns = nsL[0][tid] + nsL[1][tid] + nsL[2][tid] + nsL[3][tid];
        float un = sqrtf(fmaxf(ns, 1e-15f));
        coefL[tid] = tanhf(un) / un;
    }
    __syncthreads();
#pragma unroll
    for (int fm = 0; fm < 2; ++fm)
#pragma unroll
        for (int r = 0; r < 4; ++r) {
            const int row = fm * 16 + lh * 4 + r;
            outcat[(size_t)(b * kS + i0 + row) * kD + h * kDK + jc] = mval[fm][r] * coefL[row];
        }
}

// ---- attn_norm: in-place row expansion. Row r: first 4KB holds 2048 bf16 e-values;
// read them to registers, barrier, write all 2048 fp32 = e * invS[r]. One block/row. ----
__global__ __launch_bounds__(256) void attn_norm(float* __restrict__ attn,
                                                 const float* __restrict__ invSg) {
    const int row = blockIdx.x;
    const int t = threadIdx.x;
    const unsigned short* u = (const unsigned short*)attn + (size_t)row * 4096;
    uint4 v = *(const uint4*)(u + t * 8);
    const float is = invSg[row];
    __syncthreads();           // all reads done before any in-place overwrite
    float o[8];
    o[0] = __uint_as_float(v.x << 16) * is;
    o[1] = __uint_as_float(v.x & 0xFFFF0000u) * is;
    o[2] = __uint_as_float(v.y << 16) * is;
    o[3] = __uint_as_float(v.y & 0xFFFF0000u) * is;
    o[4] = __uint_as_float(v.z << 16) * is;
    o[5] = __uint_as_float(v.z & 0xFFFF0000u) * is;
    o[6] = __uint_as_float(v.w << 16) * is;
    o[7] = __uint_as_float(v.w & 0xFFFF0000u) * is;
    float* dst = attn + (size_t)row * kS + t * 8;
    *(float4*)dst       = make_float4(o[0], o[1], o[2], o[3]);
    *(float4*)(dst + 4) = make_float4(o[4], o[5], o[6], o[7]);
}

} // namespace

extern "C" void kernel_launch(void* const* d_in, const int* in_sizes, int n_in,
                              void* d_out, int out_size, void* d_ws, size_t ws_size,
                              hipStream_t stream) {
    const float* q  = (const float*)d_in[0];
    const float* k  = (const float*)d_in[1];
    const float* v  = (const float*)d_in[2];
    const float* Wq = (const float*)d_in[3];
    const float* bq = (const float*)d_in[4];
    const float* Wk = (const float*)d_in[5];
    const float* bk = (const float*)d_in[6];
    const float* Wv = (const float*)d_in[7];
    const float* bv = (const float*)d_in[8];
    const float* Wo = (const float*)d_in[9];
    const float* bo = (const float*)d_in[10];

    float* out  = (float*)d_out;
    float* attn = out + (size_t)kM * kD;   // out (2M floats), then attn (64M floats)

    constexpr size_t NBUF = (size_t)kM * kD; // 2,097,152 floats (8 MB)
    float* ws  = (float*)d_ws;
    float* A0  = ws;              // Qp
    float* A1  = ws + NBUF;       // Kp -> later outcat
    float* A2  = ws + 2 * NBUF;   // Vp -> Qhi/Qlo bf16 -> mx for final gemm
    float* A3  = ws + 3 * NBUF;   // mx scratch -> LVbT (4MB)
    float* qn2 = ws + 4 * NBUF;                       // 32768 floats
    float* kn2 = qn2 + (size_t)kBH * kS;              // 32768 floats
    float* invSg = kn2 + (size_t)kBH * kS;            // 32768 floats

    constexpr size_t HP = (size_t)kBH * kS * kDK;   // 2,097,152 ushorts = 4 MB per plane
    unsigned short* Qhi = (unsigned short*)A2;
    unsigned short* Qlo = Qhi + HP;
    unsigned short* Khi = (unsigned short*)out;     // out region free until final rowops
    unsigned short* Klo = Khi + HP;
    unsigned short* LVbT = (unsigned short*)A3;     // [bh][64][2048] bf16 (4 MB)

    dim3 gg(kM / 64, kD / 64);

    gemm_mfma<<<gg, 256, 0, stream>>>(q, Wq, A3);
    rowops<<<kM, 256, 0, stream>>>(q, A3, bq, A0);
    gemm_mfma<<<gg, 256, 0, stream>>>(k, Wk, A3);
    rowops<<<kM, 256, 0, stream>>>(k, A3, bk, A1);
    gemm_mfma<<<gg, 256, 0, stream>>>(v, Wv, A3);
    rowops<<<kM, 256, 0, stream>>>(v, A3, bv, A2);

    prep2<<<kBH * 32, 256, 0, stream>>>(A0, A1, A2, qn2, kn2, LVbT);

    split_qk<<<(kBH * kS) / 4, 256, 0, stream>>>(A0, A1, Qhi, Qlo, Khi, Klo);

    fused_attn<<<kBH * (kS / 32), 256, 0, stream>>>(Qhi, Qlo, Khi, Klo, LVbT,
                                                    qn2, kn2,
                                                    (unsigned short*)attn, A1, invSg);

    attn_norm<<<kBH * kS, 256, 0, stream>>>(attn, invSg);

    gemm_mfma<<<gg, 256, 0, stream>>>(A1, Wo, A2);
    rowops<<<kM, 256, 0, stream>>>(A1, A2, bo, out);
}

// Round 11
// 282.151 us; speedup vs baseline: 1.0774x; 1.0571x over previous
//
#include <hip/hip_runtime.h>
#include <math.h>

namespace {

constexpr int kB  = 2;
constexpr int kS  = 2048;
constexpr int kD  = 512;
constexpr int kH  = 8;
constexpr int kDK = 64;
constexpr int kM  = kB * kS;   // 4096 rows
constexpr int kBH = kB * kH;   // 16

typedef __attribute__((ext_vector_type(8))) short bf16x8;
typedef __attribute__((ext_vector_type(4))) float f32x4;

__device__ __forceinline__ float wave_sum64(float v) {
#pragma unroll
    for (int o = 32; o > 0; o >>= 1) v += __shfl_xor(v, o, 64);
    return v;
}

__device__ __forceinline__ unsigned short f2bf(float f) {
    unsigned u = __float_as_uint(f);
    unsigned r = (u + 0x7FFF + ((u >> 16) & 1)) >> 16;   // round-to-nearest-even
    return (unsigned short)r;
}
__device__ __forceinline__ float bf2f(unsigned short h) {
    return __uint_as_float(((unsigned)h) << 16);
}

#define MAXN_F  ((float)(1.0 - 1e-5))
#define ACLIP_F ((float)(1.0 - 1e-7))

// ---- GEMM via split-bf16 MFMA: Y(4096x512) = X(4096x512) @ W(512x512)^T ----
__global__ __launch_bounds__(256) void gemm_mfma(const float* __restrict__ X,
                                                 const float* __restrict__ W,
                                                 float* __restrict__ Y) {
    __shared__ unsigned short Ah[64 * 64], Al[64 * 64], Bh[64 * 64], Bl[64 * 64];
    const int m0 = blockIdx.x * 64;
    const int n0 = blockIdx.y * 64;
    const int tid = threadIdx.x;
    const int w = tid >> 6, l = tid & 63;
    const int lr = l & 15, lh = l >> 4;
    const int sr = tid >> 2;          // staging row 0..63
    const int sk = (tid & 3) * 16;    // staging k base (16 elems/thread)
    float4 xr[4], wr[4];
#pragma unroll
    for (int i = 0; i < 4; ++i) {
        xr[i] = *(const float4*)(X + (size_t)(m0 + sr) * 512 + sk + i * 4);
        wr[i] = *(const float4*)(W + (size_t)(n0 + sr) * 512 + sk + i * 4);
    }
    f32x4 acc[4];
#pragma unroll
    for (int j = 0; j < 4; ++j) acc[j] = (f32x4){0.f, 0.f, 0.f, 0.f};

    for (int c = 0; c < 8; ++c) {
        if (c) __syncthreads();       // previous MFMA done reading LDS
        {
            unsigned hx[8], lx[8], hw_[8], lw_[8];
#pragma unroll
            for (int t = 0; t < 8; ++t) {
                float e0 = ((const float*)&xr[t >> 1])[(t & 1) * 2 + 0];
                float e1 = ((const float*)&xr[t >> 1])[(t & 1) * 2 + 1];
                unsigned short h0 = f2bf(e0), h1 = f2bf(e1);
                hx[t] = (unsigned)h0 | ((unsigned)h1 << 16);
                lx[t] = (unsigned)f2bf(e0 - bf2f(h0)) | ((unsigned)f2bf(e1 - bf2f(h1)) << 16);
                float f0 = ((const float*)&wr[t >> 1])[(t & 1) * 2 + 0];
                float f1 = ((const float*)&wr[t >> 1])[(t & 1) * 2 + 1];
                unsigned short g0 = f2bf(f0), g1 = f2bf(f1);
                hw_[t] = (unsigned)g0 | ((unsigned)g1 << 16);
                lw_[t] = (unsigned)f2bf(f0 - bf2f(g0)) | ((unsigned)f2bf(f1 - bf2f(g1)) << 16);
            }
            const int ga = (sk >> 3) ^ (sr & 7);
            const int gb = ((sk >> 3) + 1) ^ (sr & 7);
            *(uint4*)&Ah[sr * 64 + ga * 8] = make_uint4(hx[0], hx[1], hx[2], hx[3]);
            *(uint4*)&Ah[sr * 64 + gb * 8] = make_uint4(hx[4], hx[5], hx[6], hx[7]);
            *(uint4*)&Al[sr * 64 + ga * 8] = make_uint4(lx[0], lx[1], lx[2], lx[3]);
            *(uint4*)&Al[sr * 64 + gb * 8] = make_uint4(lx[4], lx[5], lx[6], lx[7]);
            *(uint4*)&Bh[sr * 64 + ga * 8] = make_uint4(hw_[0], hw_[1], hw_[2], hw_[3]);
            *(uint4*)&Bh[sr * 64 + gb * 8] = make_uint4(hw_[4], hw_[5], hw_[6], hw_[7]);
            *(uint4*)&Bl[sr * 64 + ga * 8] = make_uint4(lw_[0], lw_[1], lw_[2], lw_[3]);
            *(uint4*)&Bl[sr * 64 + gb * 8] = make_uint4(lw_[4], lw_[5], lw_[6], lw_[7]);
        }
        if (c < 7) {
            const int k1 = (c + 1) * 64;
#pragma unroll
            for (int i = 0; i < 4; ++i) {
                xr[i] = *(const float4*)(X + (size_t)(m0 + sr) * 512 + k1 + sk + i * 4);
                wr[i] = *(const float4*)(W + (size_t)(n0 + sr) * 512 + k1 + sk + i * 4);
            }
        }
        __syncthreads();
#pragma unroll
        for (int ks = 0; ks < 2; ++ks) {
            const int kb = ks * 4 + lh;
            const int row = w * 16 + lr;
            const int aoff = row * 64 + ((kb ^ (row & 7)) << 3);
            bf16x8 ah = *(const bf16x8*)&Ah[aoff];
            bf16x8 al = *(const bf16x8*)&Al[aoff];
#pragma unroll
            for (int fn = 0; fn < 4; ++fn) {
                const int col = fn * 16 + lr;
                const int boff = col * 64 + ((kb ^ (col & 7)) << 3);
                bf16x8 bh8 = *(const bf16x8*)&Bh[boff];
                bf16x8 bl8 = *(const bf16x8*)&Bl[boff];
                acc[fn] = __builtin_amdgcn_mfma_f32_16x16x32_bf16(ah, bh8, acc[fn], 0, 0, 0);
                acc[fn] = __builtin_amdgcn_mfma_f32_16x16x32_bf16(al, bh8, acc[fn], 0, 0, 0);
                acc[fn] = __builtin_amdgcn_mfma_f32_16x16x32_bf16(ah, bl8, acc[fn], 0, 0, 0);
            }
        }
    }
#pragma unroll
    for (int fn = 0; fn < 4; ++fn)
#pragma unroll
        for (int r = 0; r < 4; ++r)
            Y[(size_t)(m0 + w * 16 + lh * 4 + r) * 512 + n0 + fn * 16 + lr] = acc[fn][r];
}

// --------- mobius_linear tail: res=matvec scale; mobius_add(res,b); project ---------
__global__ __launch_bounds__(256) void rowops(const float* __restrict__ X,
                                              const float* __restrict__ MX,
                                              const float* __restrict__ bvec,
                                              float* __restrict__ out) {
    __shared__ float4 red4[4];
    __shared__ float red1[4];
    const int row = blockIdx.x;
    const int tid = threadIdx.x;
    const float2 xv = ((const float2*)(X + (size_t)row * kD))[tid];
    const float2 mv = ((const float2*)(MX + (size_t)row * kD))[tid];
    const float2 bv = ((const float2*)bvec)[tid];
    float sx  = fmaf(xv.x, xv.x, xv.y * xv.y);
    float sm  = fmaf(mv.x, mv.x, mv.y * mv.y);
    float smb = fmaf(mv.x, bv.x, mv.y * bv.y);
    float sb  = fmaf(bv.x, bv.x, bv.y * bv.y);
#pragma unroll
    for (int o = 32; o > 0; o >>= 1) {
        sx  += __shfl_xor(sx, o, 64);
        sm  += __shfl_xor(sm, o, 64);
        smb += __shfl_xor(smb, o, 64);
        sb  += __shfl_xor(sb, o, 64);
    }
    if ((tid & 63) == 0) red4[tid >> 6] = make_float4(sx, sm, smb, sb);
    __syncthreads();
    {
        float4 r0 = red4[0], r1 = red4[1], r2 = red4[2], r3 = red4[3];
        sx  = r0.x + r1.x + r2.x + r3.x;
        sm  = r0.y + r1.y + r2.y + r3.y;
        smb = r0.z + r1.z + r2.z + r3.z;
        sb  = r0.w + r1.w + r2.w + r3.w;
    }
    float xn  = sqrtf(fmaxf(sx, 1e-15f));
    float mxn = sqrtf(fmaxf(sm, 1e-15f));
    float xc  = fminf(xn, ACLIP_F);
    float at  = 0.5f * logf((1.f + xc) / (1.f - xc));       // artanh(xn)
    float sc  = tanhf(mxn / xn * at) / mxn;                 // res = sc * mx
    if (sm == 0.f) sc = 0.f;                                // all(mx==0) branch
    float x2 = sc * sc * sm;
    float xy = sc * smb;
    float y2 = sb;
    float c1 = 1.f + 2.f * xy + y2;
    float c2 = 1.f - x2;
    float den = fmaxf(1.f + 2.f * xy + x2 * y2, 1e-15f);
    float idn = 1.f / den;
    float ux = (c1 * sc * mv.x + c2 * bv.x) * idn;
    float uy = (c1 * sc * mv.y + c2 * bv.y) * idn;
    float su = wave_sum64(fmaf(ux, ux, uy * uy));
    if ((tid & 63) == 0) red1[tid >> 6] = su;
    __syncthreads();
    su = (red1[0] + red1[1]) + (red1[2] + red1[3]);
    float n = sqrtf(fmaxf(su, 1e-15f));
    float f = (n > MAXN_F) ? (MAXN_F / n) : 1.f;
    ((float2*)(out + (size_t)row * kD))[tid] = make_float2(ux * f, uy * f);
}

// ---- prep2: per-head-row |q|^2,|k|^2 + LVbT[bh][n][k] = bf16(logmap0(V_head))^T ----
__global__ __launch_bounds__(256) void prep2(const float* __restrict__ Qp,
                                             const float* __restrict__ Kp,
                                             const float* __restrict__ Vp,
                                             float* __restrict__ qn2,
                                             float* __restrict__ kn2,
                                             unsigned short* __restrict__ LVbT) {
    __shared__ unsigned short T[64][66];   // [n][s_local], 66 -> 2-way banks (free)
    const int bh = blockIdx.x >> 5;
    const int k0 = (blockIdx.x & 31) * 64;
    const int b = bh >> 3, h = bh & 7;
    const int w = threadIdx.x >> 6, l = threadIdx.x & 63;
#pragma unroll 4
    for (int i = 0; i < 16; ++i) {
        const int s = k0 + w * 16 + i;
        const size_t src = (size_t)(b * kS + s) * kD + h * kDK + l;
        float qv = Qp[src], kv = Kp[src], vv = Vp[src];
        float sq = wave_sum64(qv * qv);
        float sk = wave_sum64(kv * kv);
        float sv = wave_sum64(vv * vv);
        if (l == 0) { qn2[(bh << 11) + s] = sq; kn2[(bh << 11) + s] = sk; }
        float yn = sqrtf(fmaxf(sv, 1e-15f));
        float yc = fminf(yn, ACLIP_F);
        float coef = 0.5f * logf((1.f + yc) / (1.f - yc)) / yn;
        T[l][w * 16 + i] = f2bf(vv * coef);
    }
    __syncthreads();
    const int n = threadIdx.x >> 2, kk = (threadIdx.x & 3) * 16;
    const unsigned int* Tr = (const unsigned int*)&T[n][kk];
    unsigned int u0 = Tr[0], u1 = Tr[1], u2 = Tr[2], u3 = Tr[3];
    unsigned int u4 = Tr[4], u5 = Tr[5], u6 = Tr[6], u7 = Tr[7];
    unsigned short* dst = LVbT + (((size_t)(bh * 64 + n)) << 11) + k0 + kk;
    *(uint4*)dst = make_uint4(u0, u1, u2, u3);
    *(uint4*)(dst + 8) = make_uint4(u4, u5, u6, u7);
}

// ---- split_qk: Q,K head-gathered -> hi/lo bf16 planes [bh][s][64] (split-precision) ----
__global__ __launch_bounds__(256) void split_qk(const float* __restrict__ Qp,
                                                const float* __restrict__ Kp,
                                                unsigned short* __restrict__ Qhi,
                                                unsigned short* __restrict__ Qlo,
                                                unsigned short* __restrict__ Khi,
                                                unsigned short* __restrict__ Klo) {
    const int gid  = blockIdx.x * 4 + (threadIdx.x >> 6);
    const int lane = threadIdx.x & 63;
    const int bh = gid >> 11, s = gid & 2047;
    const int b = bh >> 3, h = bh & 7;
    const size_t src = (size_t)(b * kS + s) * kD + h * kDK + lane;
    const size_t dst = ((size_t)gid << 6) + lane;
    float qv = Qp[src];
    unsigned short qh = f2bf(qv);
    Qhi[dst] = qh;
    Qlo[dst] = f2bf(qv - bf2f(qh));
    float kv = Kp[src];
    unsigned short kh = f2bf(kv);
    Khi[dst] = kh;
    Klo[dst] = f2bf(kv - bf2f(kh));
}

// ================= fused_attn =================
// Pass A: per 64-col tile: split-bf16 QK MFMA -> exp epilogue -> rowsum partials +
// unnormalized PV MFMA; bf16 e-tile flushed to the first 4KB of each attn row.
// Then: invS, mid scale, expmap0, outcat. Tail: in-place row expansion e->fp32 attn
// (overlaps, GPU-wide, with other blocks still in their VALU-bound pass A).
__global__ __launch_bounds__(256) void fused_attn(const unsigned short* __restrict__ Qhi,
                                                  const unsigned short* __restrict__ Qlo,
                                                  const unsigned short* __restrict__ Khi,
                                                  const unsigned short* __restrict__ Klo,
                                                  const unsigned short* __restrict__ LVbT,
                                                  const float* __restrict__ qn2,
                                                  const float* __restrict__ kn2,
                                                  float* __restrict__ attn,
                                                  float* __restrict__ outcat) {
    __shared__ unsigned short KshH[64 * 64], KshL[64 * 64], LVsh[64 * 64], Psh[32 * 64];
    __shared__ float kn2s[2048];
    __shared__ float qn2s[32];
    __shared__ float rsL[4][32], nsL[4][32];
    __shared__ float invSL[32], coefL[32];
    unsigned short* eattn = (unsigned short*)attn;

    // XCD-pair mapping: XCD x works bh {2x, 2x+1} (K/LV set ~1.5 MB fits per-XCD L2)
    const int wgid = blockIdx.x;
    const int x = wgid & 7, bq_ = wgid >> 3;
    const int bh = 2 * x + (bq_ >> 6);
    const int i0 = (bq_ & 63) * 32;
    const int b = bh >> 3, h = bh & 7;
    const int tid = threadIdx.x;
    const int w = tid >> 6, l = tid & 63;
    const int lr = l & 15, lh = l >> 4;
    const int srj = tid >> 2;            // staging row (j or dk) 0..63
    const int skk = (tid & 3) * 16;      // staging k base
    const size_t kvbase = ((size_t)(bh << 11)) << 6;     // K planes base (shorts)
    const size_t lvbase = ((size_t)bh) << 17;            // LVbT base

    {
        const float* src = kn2 + (bh << 11) + tid * 8;
        *(float4*)&kn2s[tid * 8]     = *(const float4*)src;
        *(float4*)&kn2s[tid * 8 + 4] = *(const float4*)(src + 4);
        if (tid < 32) qn2s[tid] = qn2[(bh << 11) + i0 + tid];
    }
    bf16x8 qah[2][2], qal[2][2];
#pragma unroll
    for (int fm = 0; fm < 2; ++fm)
#pragma unroll
        for (int ks = 0; ks < 2; ++ks) {
            const size_t a = ((size_t)(bh << 11) + i0 + fm * 16 + lr) * 64 + (ks * 4 + lh) * 8;
            qah[fm][ks] = *(const bf16x8*)&Qhi[a];
            qal[fm][ks] = *(const bf16x8*)&Qlo[a];
        }

    const int ga = (((skk >> 3) ^ (srj & 7)) << 3);
    const int gb = ((((skk >> 3) + 1) ^ (srj & 7)) << 3);
    const int jc = w * 16 + lr;          // this wave's col (j in QK n-frag / dk in PV)
    uint4 pA0, pA1, pB0, pB1, pC0, pC1;
    {
        const unsigned short* kh = Khi + kvbase + (size_t)srj * 64 + skk;
        const unsigned short* kl = Klo + kvbase + (size_t)srj * 64 + skk;
        const unsigned short* lv = LVbT + lvbase + (size_t)srj * 2048 + skk;
        pA0 = *(const uint4*)kh; pA1 = *(const uint4*)(kh + 8);
        pB0 = *(const uint4*)kl; pB1 = *(const uint4*)(kl + 8);
        pC0 = *(const uint4*)lv; pC1 = *(const uint4*)(lv + 8);
    }

    f32x4 pvacc[2];
    pvacc[0] = (f32x4){0.f, 0.f, 0.f, 0.f};
    pvacc[1] = (f32x4){0.f, 0.f, 0.f, 0.f};
    float rsp[2][4] = {};

    __syncthreads();   // qn2s ready
    // hoist per-row epilogue constants to registers (LDS reads once, not per tile)
    float x2r_[2][4];
#pragma unroll
    for (int fm = 0; fm < 2; ++fm)
#pragma unroll
        for (int r = 0; r < 4; ++r) x2r_[fm][r] = qn2s[fm * 16 + lh * 4 + r];

    for (int t = 0; t < 32; ++t) {
        const int j0 = t * 64;
        if (t) __syncthreads();
        *(uint4*)&KshH[srj * 64 + ga] = pA0; *(uint4*)&KshH[srj * 64 + gb] = pA1;
        *(uint4*)&KshL[srj * 64 + ga] = pB0; *(uint4*)&KshL[srj * 64 + gb] = pB1;
        *(uint4*)&LVsh[srj * 64 + ga] = pC0; *(uint4*)&LVsh[srj * 64 + gb] = pC1;
        if (t < 31) {
            const unsigned short* kh = Khi + kvbase + (size_t)(j0 + 64 + srj) * 64 + skk;
            const unsigned short* kl = Klo + kvbase + (size_t)(j0 + 64 + srj) * 64 + skk;
            const unsigned short* lv = LVbT + lvbase + (size_t)srj * 2048 + j0 + 64 + skk;
            pA0 = *(const uint4*)kh; pA1 = *(const uint4*)(kh + 8);
            pB0 = *(const uint4*)kl; pB1 = *(const uint4*)(kl + 8);
            pC0 = *(const uint4*)lv; pC1 = *(const uint4*)(lv + 8);
        }
        __syncthreads();
        f32x4 sacc[2];
        sacc[0] = (f32x4){0.f, 0.f, 0.f, 0.f};
        sacc[1] = (f32x4){0.f, 0.f, 0.f, 0.f};
#pragma unroll
        for (int ks = 0; ks < 2; ++ks) {
            const int kb = ks * 4 + lh;
            const int boff = jc * 64 + ((kb ^ (jc & 7)) << 3);
            bf16x8 bh8 = *(const bf16x8*)&KshH[boff];
            bf16x8 bl8 = *(const bf16x8*)&KshL[boff];
#pragma unroll
            for (int fm = 0; fm < 2; ++fm) {
                sacc[fm] = __builtin_amdgcn_mfma_f32_16x16x32_bf16(qah[fm][ks], bh8, sacc[fm], 0, 0, 0);
                sacc[fm] = __builtin_amdgcn_mfma_f32_16x16x32_bf16(qal[fm][ks], bh8, sacc[fm], 0, 0, 0);
                sacc[fm] = __builtin_amdgcn_mfma_f32_16x16x32_bf16(qah[fm][ks], bl8, sacc[fm], 0, 0, 0);
            }
        }
        const float y2 = kn2s[j0 + jc];
        const int pg = jc >> 3, pw = jc & 7;
#pragma unroll
        for (int fm = 0; fm < 2; ++fm)
#pragma unroll
            for (int r = 0; r < 4; ++r) {
                const int row = fm * 16 + lh * 4 + r;
                float xy = sacc[fm][r];
                float x2 = x2r_[fm][r];
                float A_ = 1.f - 2.f * xy + y2;
                float Bc = 1.f - x2;
                float num2 = A_ * A_ * x2 + Bc * Bc * y2 - 2.f * A_ * Bc * xy;
                float den  = fmaxf(1.f - 2.f * xy + x2 * y2, 1e-15f);
                float sn   = __builtin_amdgcn_sqrtf(fmaxf(num2, 0.f));
                float dm   = den - sn;
                dm = fmaxf(dm, (den + sn) * 5e-8f);
                float rr = (den + sn) * __builtin_amdgcn_rcpf(dm);
                float e = __builtin_amdgcn_exp2f(-0.125f * __builtin_amdgcn_logf(rr));
                rsp[fm][r] += e;
                Psh[row * 64 + ((pg ^ (row & 7)) << 3) + pw] = f2bf(e);
            }
        __syncthreads();
#pragma unroll
        for (int ks = 0; ks < 2; ++ks) {
            const int kb = ks * 4 + lh;
            bf16x8 bv8 = *(const bf16x8*)&LVsh[jc * 64 + ((kb ^ (jc & 7)) << 3)];
#pragma unroll
            for (int fm = 0; fm < 2; ++fm) {
                const int prow = fm * 16 + lr;
                bf16x8 pa = *(const bf16x8*)&Psh[prow * 64 + ((kb ^ (prow & 7)) << 3)];
                pvacc[fm] = __builtin_amdgcn_mfma_f32_16x16x32_bf16(pa, bv8, pvacc[fm], 0, 0, 0);
            }
        }
        // coalesced e-tile flush into the FIRST HALF of each attn row (bf16)
        {
            const int prow = tid >> 3, g = tid & 7;
            uint4 ev = *(const uint4*)&Psh[prow * 64 + ((g ^ (prow & 7)) << 3)];
            *(uint4*)(eattn + ((size_t)(bh << 11) + i0 + prow) * 4096 + j0 + g * 8) = ev;
        }
    }
    __syncthreads();
#pragma unroll
    for (int fm = 0; fm < 2; ++fm)
#pragma unroll
        for (int r = 0; r < 4; ++r) {
            float v = rsp[fm][r];
            v += __shfl_xor(v, 1, 64); v += __shfl_xor(v, 2, 64);
            v += __shfl_xor(v, 4, 64); v += __shfl_xor(v, 8, 64);
            rsp[fm][r] = v;
        }
    if (lr == 0) {
#pragma unroll
        for (int fm = 0; fm < 2; ++fm)
#pragma unroll
            for (int r = 0; r < 4; ++r) rsL[w][fm * 16 + lh * 4 + r] = rsp[fm][r];
    }
    __syncthreads();
    if (tid < 32)
        invSL[tid] = 1.f / (rsL[0][tid] + rsL[1][tid] + rsL[2][tid] + rsL[3][tid]);
    __syncthreads();
    float mval[2][4];
#pragma unroll
    for (int fm = 0; fm < 2; ++fm)
#pragma unroll
        for (int r = 0; r < 4; ++r) {
            const int row = fm * 16 + lh * 4 + r;
            float m = pvacc[fm][r] * invSL[row];
            mval[fm][r] = m;
            float ns = m * m;
            ns += __shfl_xor(ns, 1, 64); ns += __shfl_xor(ns, 2, 64);
            ns += __shfl_xor(ns, 4, 64); ns += __shfl_xor(ns, 8, 64);
            if (lr == 0) nsL[w][row] = ns;
        }
    __syncthreads();
    if (tid < 32) {
        float ns = nsL[0][tid] + nsL[1][tid] + nsL[2][tid] + nsL[3][tid];
        float un = sqrtf(fmaxf(ns, 1e-15f));
        coefL[tid] = tanhf(un) / un;
    }
    __syncthreads();
#pragma unroll
    for (int fm = 0; fm < 2; ++fm)
#pragma unroll
        for (int r = 0; r < 4; ++r) {
            const int row = fm * 16 + lh * 4 + r;
            outcat[(size_t)(b * kS + i0 + row) * kD + h * kDK + jc] = mval[fm][r] * coefL[row];
        }

    // ---- tail: in-place expansion of this block's 32 rows: e(bf16) -> fp32 attn ----
    // Per row: all 256 threads read the row's 2048 bf16 (uint4 each), barrier (the
    // fp32 write of float col c overwrites e cols 2c..2c+1 — different thread), write.
    // Rows don't alias each other, so only one barrier per row is needed.
    for (int r = 0; r < 32; ++r) {
        const size_t rowbase = (size_t)(bh << 11) + i0 + r;
        uint4 ev = *(const uint4*)(eattn + rowbase * 4096 + tid * 8);
        const float is = invSL[r];
        __syncthreads();          // all reads of row r complete before any overwrite
        float o[8];
        o[0] = __uint_as_float(ev.x << 16) * is;
        o[1] = __uint_as_float(ev.x & 0xFFFF0000u) * is;
        o[2] = __uint_as_float(ev.y << 16) * is;
        o[3] = __uint_as_float(ev.y & 0xFFFF0000u) * is;
        o[4] = __uint_as_float(ev.z << 16) * is;
        o[5] = __uint_as_float(ev.z & 0xFFFF0000u) * is;
        o[6] = __uint_as_float(ev.w << 16) * is;
        o[7] = __uint_as_float(ev.w & 0xFFFF0000u) * is;
        float* dst = attn + rowbase * kS + tid * 8;
        *(float4*)dst       = make_float4(o[0], o[1], o[2], o[3]);
        *(float4*)(dst + 4) = make_float4(o[4], o[5], o[6], o[7]);
    }
}

} // namespace

extern "C" void kernel_launch(void* const* d_in, const int* in_sizes, int n_in,
                              void* d_out, int out_size, void* d_ws, size_t ws_size,
                              hipStream_t stream) {
    const float* q  = (const float*)d_in[0];
    const float* k  = (const float*)d_in[1];
    const float* v  = (const float*)d_in[2];
    const float* Wq = (const float*)d_in[3];
    const float* bq = (const float*)d_in[4];
    const float* Wk = (const float*)d_in[5];
    const float* bk = (const float*)d_in[6];
    const float* Wv = (const float*)d_in[7];
    const float* bv = (const float*)d_in[8];
    const float* Wo = (const float*)d_in[9];
    const float* bo = (const float*)d_in[10];

    float* out  = (float*)d_out;
    float* attn = out + (size_t)kM * kD;   // out (2M floats), then attn (64M floats)

    constexpr size_t NBUF = (size_t)kM * kD; // 2,097,152 floats (8 MB)
    float* ws  = (float*)d_ws;
    float* A0  = ws;              // Qp
    float* A1  = ws + NBUF;       // Kp -> later outcat
    float* A2  = ws + 2 * NBUF;   // Vp -> Qhi/Qlo bf16 -> mx for final gemm
    float* A3  = ws + 3 * NBUF;   // mx scratch -> LVbT (4MB)
    float* qn2 = ws + 4 * NBUF;                       // 32768 floats
    float* kn2 = qn2 + (size_t)kBH * kS;              // 32768 floats

    constexpr size_t HP = (size_t)kBH * kS * kDK;   // 2,097,152 ushorts = 4 MB per plane
    unsigned short* Qhi = (unsigned short*)A2;
    unsigned short* Qlo = Qhi + HP;
    unsigned short* Khi = (unsigned short*)out;     // out region free until final rowops
    unsigned short* Klo = Khi + HP;
    unsigned short* LVbT = (unsigned short*)A3;     // [bh][64][2048] bf16 (4 MB)

    dim3 gg(kM / 64, kD / 64);

    gemm_mfma<<<gg, 256, 0, stream>>>(q, Wq, A3);
    rowops<<<kM, 256, 0, stream>>>(q, A3, bq, A0);
    gemm_mfma<<<gg, 256, 0, stream>>>(k, Wk, A3);
    rowops<<<kM, 256, 0, stream>>>(k, A3, bk, A1);
    gemm_mfma<<<gg, 256, 0, stream>>>(v, Wv, A3);
    rowops<<<kM, 256, 0, stream>>>(v, A3, bv, A2);

    prep2<<<kBH * 32, 256, 0, stream>>>(A0, A1, A2, qn2, kn2, LVbT);

    split_qk<<<(kBH * kS) / 4, 256, 0, stream>>>(A0, A1, Qhi, Qlo, Khi, Klo);

    fused_attn<<<kBH * (kS / 32), 256, 0, stream>>>(Qhi, Qlo, Khi, Klo, LVbT,
                                                    qn2, kn2, attn, A1);

    gemm_mfma<<<gg, 256, 0, stream>>>(A1, Wo, A2);
    rowops<<<kM, 256, 0, stream>>>(A1, A2, bo, out);
}